// Round 7
// baseline (992.563 us; speedup 1.0000x reference)
//
#include <hip/hip_runtime.h>

#define NODES 100000
#define EDGES 1600000
#define FEATS 128
#define NCLS  16

// bucket = 64 consecutive dst nodes
#define BSH    6
#define BNODES 64
#define NB     ((NODES + BNODES - 1) / BNODES)   // 1563
#define CHUNK  8192
#define NBLK   ((EDGES + CHUNK - 1) / CHUNK)     // 196
#define NHIST  (NB * NBLK)                       // 306348
#define BCAP   2048                              // per-bucket LDS capacity
#define SLST   ((NODES + 1) * 16)                // u16 elems per 16-feat slice (+pad row)

typedef unsigned int  u32;
typedef unsigned short u16;
typedef __attribute__((ext_vector_type(8))) short short8;
typedef __attribute__((ext_vector_type(4))) float f32x4;

__device__ __forceinline__ u16 f2b(float f){
  u32 u = __float_as_uint(f);
  u += 0x7fffu + ((u>>16)&1u);   // RNE
  return (u16)(u>>16);
}
__device__ __forceinline__ float blo(u32 p){ return __uint_as_float(p<<16); }
__device__ __forceinline__ float bhi(u32 p){ return __uint_as_float(p & 0xffff0000u); }

// ---------------- phase A: per-chunk bucket histogram ----------------

__global__ __launch_bounds__(256) void pA_k(const int* __restrict__ dst,
                                            int* __restrict__ gh, int E){
  __shared__ int hist[NB];
  int t = threadIdx.x, blk = blockIdx.x;
  for (int j = t; j < NB; j += 256) hist[j] = 0;
  __syncthreads();
  int e0 = blk*CHUNK, e1 = e0 + CHUNK; if (e1 > E) e1 = E;
  for (int e = e0 + t; e < e1; e += 256) atomicAdd(&hist[dst[e] >> BSH], 1);
  __syncthreads();
  for (int j = t; j < NB; j += 256) gh[j*NBLK + blk] = hist[j];
}

// ---------------- phase B: exclusive scan of gh ----------------

__global__ __launch_bounds__(256) void scan1_k(const int* __restrict__ in, int* __restrict__ out,
                                               int* __restrict__ bsum, int n){
  __shared__ int sh[256];
  int t = threadIdx.x;
  int base = blockIdx.x*2048 + t*8;
  int v[8]; int s = 0;
  #pragma unroll
  for (int j=0;j<8;++j) v[j] = (base+j < n) ? in[base+j] : 0;
  #pragma unroll
  for (int j=0;j<8;++j){ int tmp = v[j]; v[j] = s; s += tmp; }
  sh[t] = s; __syncthreads();
  for (int off=1; off<256; off<<=1){
    int x = (t>=off) ? sh[t-off] : 0;
    __syncthreads();
    sh[t] += x;
    __syncthreads();
  }
  int excl = sh[t] - s;
  #pragma unroll
  for (int j=0;j<8;++j) if (base+j < n) out[base+j] = excl + v[j];
  if (t == 255) bsum[blockIdx.x] = sh[255];
}

__global__ __launch_bounds__(256) void scan2_k(const int* __restrict__ bsum,
                                               int* __restrict__ boff, int nb){
  __shared__ int sh[256];
  int t = threadIdx.x;
  int v = (t < nb) ? bsum[t] : 0;
  sh[t] = v; __syncthreads();
  for (int off=1; off<256; off<<=1){
    int x = (t>=off) ? sh[t-off] : 0;
    __syncthreads();
    sh[t] += x;
    __syncthreads();
  }
  if (t < nb) boff[t] = sh[t] - v;
}

__global__ void scan3_k(int* __restrict__ gscan, const int* __restrict__ boff,
                        int* __restrict__ bstart, int n){
  int i = blockIdx.x*256 + threadIdx.x;
  if (i < n){
    int v = gscan[i] + boff[i>>11];
    gscan[i] = v;
    if (i % NBLK == 0) bstart[i / NBLK] = v;
    if (i == 0) bstart[NB] = EDGES;
  }
}

// ---------------- phase C: LDS counting sort, streamed coalesced write ----------------

__global__ __launch_bounds__(256) void pC_k(const int* __restrict__ src,
    const int* __restrict__ dst, const int* __restrict__ gscan,
    u32* __restrict__ elist, int E){
  __shared__ int A[NB];        // hist -> excl -> delta
  __shared__ int B[NB];        // running local position
  __shared__ int sp[256];
  __shared__ u32 pay[CHUNK];
  __shared__ u16 bkt[CHUNK];
  int t = threadIdx.x, blk = blockIdx.x;
  for (int j = t; j < NB; j += 256) A[j] = 0;
  __syncthreads();
  int e0 = blk*CHUNK, e1 = e0 + CHUNK; if (e1 > E) e1 = E;
  int cnt = e1 - e0;
  for (int e = e0 + t; e < e1; e += 256) atomicAdd(&A[dst[e] >> BSH], 1);
  __syncthreads();
  {
    int base = t*7;
    int cv[7]; int s = 0;
    #pragma unroll
    for (int j=0;j<7;++j){ int idx = base+j; cv[j] = (idx < NB) ? A[idx] : 0; s += cv[j]; }
    sp[t] = s; __syncthreads();
    for (int off=1; off<256; off<<=1){
      int x = (t>=off) ? sp[t-off] : 0;
      __syncthreads();
      sp[t] += x;
      __syncthreads();
    }
    int run = sp[t] - s;
    #pragma unroll
    for (int j=0;j<7;++j){
      int idx = base+j;
      if (idx < NB){ A[idx] = run; B[idx] = run; run += cv[j]; }
    }
  }
  __syncthreads();
  for (int j = t; j < NB; j += 256) A[j] = gscan[j*NBLK + blk] - A[j];
  __syncthreads();
  for (int e = e0 + t; e < e1; e += 256){
    int d = dst[e];
    int b = d >> BSH;
    u32 w = ((u32)(d & (BNODES-1)) << 17) | (u32)src[e];
    int r = atomicAdd(&B[b], 1);
    pay[r] = w; bkt[r] = (u16)b;
  }
  __syncthreads();
  for (int i = t; i < cnt; i += 256){
    int b = bkt[i];
    elist[i + A[b]] = pay[i];
  }
}

// ---------------- per-bucket counting sort (in place) + degrees ----------------

__global__ __launch_bounds__(256) void csr_k(u32* __restrict__ elist,
    const int* __restrict__ bstart, int* __restrict__ offs, int* __restrict__ degs,
    float* __restrict__ invd, int M){
  __shared__ int hist[BNODES];
  __shared__ int pos[BNODES];
  __shared__ u32 buf[BCAP];
  __shared__ u32 buf2[BCAP];
  int b = blockIdx.x, t = threadIdx.x;
  if (t < BNODES) hist[t] = 0;
  __syncthreads();
  int s0 = bstart[b];
  int cnt = bstart[b+1] - s0; if (cnt > BCAP) cnt = BCAP;
  u32* el = elist + s0;
  for (int e = t; e < cnt; e += 256){
    u32 w = el[e];
    buf[e] = w;
    atomicAdd(&hist[w>>17], 1);
  }
  __syncthreads();
  if (t < BNODES){
    int v = hist[t];
    int s = v;
    for (int off = 1; off < BNODES; off <<= 1){
      int x = __shfl_up(s, off);
      if (t >= off) s += x;
    }
    int excl = s - v;
    pos[t] = excl;
    int node = b*BNODES + t;
    if (node < M){
      offs[node] = s0 + excl;
      degs[node] = v;
      invd[node] = 1.f / fmaxf((float)v, 1.f);
    }
  }
  __syncthreads();
  for (int e = t; e < cnt; e += 256){
    u32 w = buf[e];
    int p = atomicAdd(&pos[w>>17], 1);
    buf2[p] = w & 0x1FFFFu;
  }
  __syncthreads();
  for (int e = t; e < cnt; e += 256) el[e] = buf2[e];
}

// ---------------- merged conversion: feats->sliced bf16, 4x weight transpose, zero pads ----

__global__ __launch_bounds__(256) void conv_k(const float* __restrict__ feats,
    const float* __restrict__ W0, const float* __restrict__ W1,
    const float* __restrict__ W2, const float* __restrict__ W3,
    u16* __restrict__ hb, u16* __restrict__ h2,
    u16* __restrict__ Wt0, u16* __restrict__ Wt1,
    u16* __restrict__ Wt2, u16* __restrict__ Wt3){
  int i = blockIdx.x*256 + threadIdx.x;
  const int NF4 = NODES*32;                     // float4 groups of features
  if (i < NF4){
    int n = i >> 5, f4 = i & 31;
    float4 x = ((const float4*)feats)[i];
    uint2 r;
    r.x = (u32)f2b(x.x) | ((u32)f2b(x.y) << 16);
    r.y = (u32)f2b(x.z) | ((u32)f2b(x.w) << 16);
    int sl = f4 >> 2, inner = (f4 & 3)*4;
    *(uint2*)(hb + (size_t)sl*SLST + n*16 + inner) = r;
    return;
  }
  i -= NF4;
  if (i < 3*16384){                             // W0..W2 transpose [K][N]->[N][K]
    int w = i / 16384, r = i % 16384;
    const float* W = (w==0) ? W0 : (w==1) ? W1 : W2;
    u16* Wt = (w==0) ? Wt0 : (w==1) ? Wt1 : Wt2;
    int k = r >> 7, nn = r & 127;
    Wt[nn*128 + k] = f2b(W[r]);
    return;
  }
  i -= 3*16384;
  if (i < 2048){                                // W3 transpose
    int k = i >> 4, nn = i & 15;
    Wt3[nn*128 + k] = f2b(W3[i]);
    return;
  }
  i -= 2048;
  if (i < 256){                                 // zero pad rows (src=NODES trick)
    int buf = i >> 7, j = i & 127;
    int sl = j >> 4, inner = j & 15;
    u16* h = buf ? h2 : hb;
    h[(size_t)sl*SLST + NODES*16 + inner] = 0;
  }
}

// ---------------- sliced aggregation: z = (1+eps)h + mean_agg(h), per 16-feat slice ----
// grid = NB*8; slice = blockIdx & 7 -> XCD-pinned (round-robin dispatch heuristic);
// each XCD's gathers then hit its own L2 (slice = 3.2 MB < 4 MB).
// lane: c = feat quad (uint2 = 4 feats), eg = 16 parallel edges. deg~16 -> 1 gather/node.

__global__ __launch_bounds__(256) void aggS_k(const u16* __restrict__ hs,
    const u32* __restrict__ el_g, const int* __restrict__ bstart,
    const int* __restrict__ offs, const int* __restrict__ degs,
    const float* __restrict__ invd, const float* __restrict__ epsv, int ei,
    u16* __restrict__ zs, int M){
  __shared__ u32 el[BCAP];
  int blk = blockIdx.x;
  int s = blk & 7;
  int b = blk >> 3;
  int t = threadIdx.x;
  int s0 = bstart[b];
  int cnt = bstart[b+1] - s0; if (cnt > BCAP) cnt = BCAP;
  for (int i = t; i < cnt; i += 256) el[i] = el_g[s0 + i];
  __syncthreads();
  const uint2* __restrict__ hsl = (const uint2*)(hs + (size_t)s*SLST);
  uint2* __restrict__ zsl = (uint2*)(zs + (size_t)s*SLST);
  int lane = t & 63, wave = t >> 6;
  int c  = lane & 3;
  int eg = lane >> 2;
  float e1s = 1.f + epsv[ei];
  int n0 = b*64 + wave*16;
  #pragma unroll 2
  for (int i = 0; i < 16; ++i){
    int n = n0 + i;
    if (n >= M) break;
    int st = offs[n] - s0, d = degs[n];
    float a0=0.f, a1=0.f, a2=0.f, a3=0.f;
    for (int e0 = 0; e0 < d; e0 += 16){
      int idx = e0 + eg;
      int src = (idx < d) ? (int)el[st + idx] : NODES;   // pad row = zeros
      uint2 p = hsl[(size_t)src*4 + c];
      a0 += blo(p.x); a1 += bhi(p.x); a2 += blo(p.y); a3 += bhi(p.y);
    }
    a0 += __shfl_xor(a0,4); a0 += __shfl_xor(a0,8); a0 += __shfl_xor(a0,16); a0 += __shfl_xor(a0,32);
    a1 += __shfl_xor(a1,4); a1 += __shfl_xor(a1,8); a1 += __shfl_xor(a1,16); a1 += __shfl_xor(a1,32);
    a2 += __shfl_xor(a2,4); a2 += __shfl_xor(a2,8); a2 += __shfl_xor(a2,16); a2 += __shfl_xor(a2,32);
    a3 += __shfl_xor(a3,4); a3 += __shfl_xor(a3,8); a3 += __shfl_xor(a3,16); a3 += __shfl_xor(a3,32);
    if (eg == 0){
      uint2 pv = hsl[(size_t)n*4 + c];
      float inv = invd[n];
      uint2 r;
      r.x = (u32)f2b(e1s*blo(pv.x) + inv*a0) | ((u32)f2b(e1s*bhi(pv.x) + inv*a1) << 16);
      r.y = (u32)f2b(e1s*blo(pv.y) + inv*a2) | ((u32)f2b(e1s*bhi(pv.y) + inv*a3) << 16);
      zsl[(size_t)n*4 + c] = r;
    }
  }
}

// ---------------- GEMM with epilogue: h' = act(z @ W + b), sliced in / sliced or f32 out ----

template<int NT, bool RELU>
__global__ __launch_bounds__(256) void gemmE_k(const u16* __restrict__ zs,
    const u16* __restrict__ Wt, const float* __restrict__ bias,
    u16* __restrict__ hout, float* __restrict__ fout, int M){
  int lane = threadIdx.x & 63;
  int wave = threadIdx.x >> 6;
  int m = lane & 15;
  int q = lane >> 4;
  int row0 = (blockIdx.x*4 + wave)*16;
  if (row0 >= M) return;
  int rowA = row0 + m; if (rowA > M-1) rowA = M-1;
  // A from sliced z: f = kk + q*8 -> slice f>>4, inner (q&1)*8
  const u16* pa = zs + (size_t)(q>>1)*SLST + (size_t)rowA*16 + (q&1)*8;

  f32x4 acc[NT];
  #pragma unroll
  for (int j=0;j<NT;++j) acc[j] = (f32x4){0.f,0.f,0.f,0.f};

  #pragma unroll
  for (int kk=0; kk<128; kk+=32){
    short8 a = *(const short8*)(pa + (size_t)(kk>>4)*SLST);
    #pragma unroll
    for (int j=0;j<NT;++j){
      short8 bf = *(const short8*)(Wt + (j*16 + m)*128 + kk + q*8);
      acc[j] = __builtin_amdgcn_mfma_f32_16x16x32_bf16(a, bf, acc[j], 0, 0, 0);
    }
  }

  #pragma unroll
  for (int j=0;j<NT;++j){
    float bj = bias[j*16 + m];
    #pragma unroll
    for (int r=0;r<4;++r){
      int gn = row0 + q*4 + r;                   // C/D: row = q*4 + r, col = m
      if (gn < M){
        float o = acc[j][r] + bj;
        if (RELU) o = fmaxf(o, 0.f);
        if (NT == 8) hout[(size_t)j*SLST + (size_t)gn*16 + m] = f2b(o);
        else         fout[(size_t)gn*16 + m] = o;
      }
    }
  }
}

// ---------------- launch ----------------

extern "C" void kernel_launch(void* const* d_in, const int* in_sizes, int n_in,
                              void* d_out, int out_size, void* d_ws, size_t ws_size,
                              hipStream_t stream){
  const float* feats = (const float*)d_in[0];
  const int*   src   = (const int*)d_in[1];
  const int*   dst   = (const int*)d_in[2];
  const float* W0 = (const float*)d_in[3];  const float* b0 = (const float*)d_in[4];
  const float* W1 = (const float*)d_in[5];  const float* b1 = (const float*)d_in[6];
  const float* W2 = (const float*)d_in[7];  const float* b2 = (const float*)d_in[8];
  const float* W3 = (const float*)d_in[9];  const float* b3 = (const float*)d_in[10];
  const float* eps = (const float*)d_in[11];

  char* w = (char*)d_ws;
  auto alloc = [&](size_t bytes)->char*{
    char* p = w; w += (bytes + 255) & ~(size_t)255; return p;
  };
  int*  gh    = (int*)alloc(sizeof(int)*NHIST);
  int*  gscan = (int*)alloc(sizeof(int)*NHIST);
  int*  bsum  = (int*)alloc(sizeof(int)*256);
  int*  boff  = (int*)alloc(sizeof(int)*256);
  int*  bstart= (int*)alloc(sizeof(int)*(NB+1));
  int*  offs  = (int*)alloc(sizeof(int)*NODES);
  int*  degs  = (int*)alloc(sizeof(int)*NODES);
  float* invd = (float*)alloc(sizeof(float)*NODES);
  u32*  elist = (u32*)alloc(sizeof(u32)*EDGES);
  u16*  hb    = (u16*)alloc(sizeof(u16)*(size_t)8*SLST);
  u16*  h2    = (u16*)alloc(sizeof(u16)*(size_t)8*SLST);
  u16*  zsb   = (u16*)alloc(sizeof(u16)*(size_t)8*SLST);
  u16*  Wt0   = (u16*)alloc(sizeof(u16)*128*128);
  u16*  Wt1   = (u16*)alloc(sizeof(u16)*128*128);
  u16*  Wt2   = (u16*)alloc(sizeof(u16)*128*128);
  u16*  Wt3   = (u16*)alloc(sizeof(u16)*16*128);

  // ---- deterministic 3-phase partition -> dense bucketed elist, per-node CSR ----
  pA_k<<<NBLK, 256, 0, stream>>>(dst, gh, EDGES);
  int snb = (NHIST + 2047)/2048;                 // 150 <= 256
  scan1_k<<<snb, 256, 0, stream>>>(gh, gscan, bsum, NHIST);
  scan2_k<<<1, 256, 0, stream>>>(bsum, boff, snb);
  scan3_k<<<(NHIST+255)/256, 256, 0, stream>>>(gscan, boff, bstart, NHIST);
  pC_k<<<NBLK, 256, 0, stream>>>(src, dst, gscan, elist, EDGES);
  csr_k<<<NB, 256, 0, stream>>>(elist, bstart, offs, degs, invd, NODES);

  // ---- conversions (sliced h layout) + weight transposes + pad-row zeros ----
  {
    int total = NODES*32 + 3*16384 + 2048 + 256;
    conv_k<<<(total+255)/256, 256, 0, stream>>>(feats, W0, W1, W2, W3,
                                                hb, h2, Wt0, Wt1, Wt2, Wt3);
  }

  int gblocks = (NODES + 63)/64;
  int sblocks = NB*8;

  // layer l: z = (1+eps_l)h + mean_agg(h);  h' = relu(z@W_l + b_l)
  aggS_k<<<sblocks, 256, 0, stream>>>(hb, elist, bstart, offs, degs, invd, eps, 0, zsb, NODES);
  gemmE_k<8,true><<<gblocks, 256, 0, stream>>>(zsb, Wt0, b0, h2, nullptr, NODES);
  aggS_k<<<sblocks, 256, 0, stream>>>(h2, elist, bstart, offs, degs, invd, eps, 1, zsb, NODES);
  gemmE_k<8,true><<<gblocks, 256, 0, stream>>>(zsb, Wt1, b1, hb, nullptr, NODES);
  aggS_k<<<sblocks, 256, 0, stream>>>(hb, elist, bstart, offs, degs, invd, eps, 2, zsb, NODES);
  gemmE_k<8,true><<<gblocks, 256, 0, stream>>>(zsb, Wt2, b2, h2, nullptr, NODES);

  // layer 3: z = (1+eps_3)h + mean_agg(h); out = z@W3 + b3 (f32, no relu)
  aggS_k<<<sblocks, 256, 0, stream>>>(h2, elist, bstart, offs, degs, invd, eps, 3, zsb, NODES);
  gemmE_k<1,false><<<gblocks, 256, 0, stream>>>(zsb, Wt3, b3, nullptr, (float*)d_out, NODES);
}

// Round 8
// 554.149 us; speedup vs baseline: 1.7911x; 1.7911x over previous
//
#include <hip/hip_runtime.h>

#define NODES 100000
#define EDGES 1600000
#define FEATS 128
#define NCLS  16

// bucket = 64 consecutive dst nodes
#define BSH    6
#define BNODES 64
#define NB     ((NODES + BNODES - 1) / BNODES)   // 1563
#define CHUNK  8192
#define NBLK   ((EDGES + CHUNK - 1) / CHUNK)     // 196
#define NHIST  (NB * NBLK)                       // 306348
#define BCAP   2048                              // per-bucket LDS capacity
#define SLST   ((NODES + 1) * 16)                // u16 elems per 16-feat slice (+pad row)

typedef unsigned int  u32;
typedef unsigned short u16;
typedef __attribute__((ext_vector_type(8))) short short8;
typedef __attribute__((ext_vector_type(4))) float f32x4;

__device__ __forceinline__ u16 f2b(float f){
  u32 u = __float_as_uint(f);
  u += 0x7fffu + ((u>>16)&1u);   // RNE
  return (u16)(u>>16);
}
__device__ __forceinline__ float blo(u32 p){ return __uint_as_float(p<<16); }
__device__ __forceinline__ float bhi(u32 p){ return __uint_as_float(p & 0xffff0000u); }

// ---------------- phase A: per-chunk bucket histogram ----------------

__global__ __launch_bounds__(256) void pA_k(const int* __restrict__ dst,
                                            int* __restrict__ gh, int E){
  __shared__ int hist[NB];
  int t = threadIdx.x, blk = blockIdx.x;
  for (int j = t; j < NB; j += 256) hist[j] = 0;
  __syncthreads();
  int e0 = blk*CHUNK, e1 = e0 + CHUNK; if (e1 > E) e1 = E;
  for (int e = e0 + t; e < e1; e += 256) atomicAdd(&hist[dst[e] >> BSH], 1);
  __syncthreads();
  for (int j = t; j < NB; j += 256) gh[j*NBLK + blk] = hist[j];
}

// ---------------- phase B: exclusive scan of gh ----------------

__global__ __launch_bounds__(256) void scan1_k(const int* __restrict__ in, int* __restrict__ out,
                                               int* __restrict__ bsum, int n){
  __shared__ int sh[256];
  int t = threadIdx.x;
  int base = blockIdx.x*2048 + t*8;
  int v[8]; int s = 0;
  #pragma unroll
  for (int j=0;j<8;++j) v[j] = (base+j < n) ? in[base+j] : 0;
  #pragma unroll
  for (int j=0;j<8;++j){ int tmp = v[j]; v[j] = s; s += tmp; }
  sh[t] = s; __syncthreads();
  for (int off=1; off<256; off<<=1){
    int x = (t>=off) ? sh[t-off] : 0;
    __syncthreads();
    sh[t] += x;
    __syncthreads();
  }
  int excl = sh[t] - s;
  #pragma unroll
  for (int j=0;j<8;++j) if (base+j < n) out[base+j] = excl + v[j];
  if (t == 255) bsum[blockIdx.x] = sh[255];
}

__global__ __launch_bounds__(256) void scan2_k(const int* __restrict__ bsum,
                                               int* __restrict__ boff, int nb){
  __shared__ int sh[256];
  int t = threadIdx.x;
  int v = (t < nb) ? bsum[t] : 0;
  sh[t] = v; __syncthreads();
  for (int off=1; off<256; off<<=1){
    int x = (t>=off) ? sh[t-off] : 0;
    __syncthreads();
    sh[t] += x;
    __syncthreads();
  }
  if (t < nb) boff[t] = sh[t] - v;
}

__global__ void scan3_k(int* __restrict__ gscan, const int* __restrict__ boff,
                        int* __restrict__ bstart, int n){
  int i = blockIdx.x*256 + threadIdx.x;
  if (i < n){
    int v = gscan[i] + boff[i>>11];
    gscan[i] = v;
    if (i % NBLK == 0) bstart[i / NBLK] = v;
    if (i == 0) bstart[NB] = EDGES;
  }
}

// ---------------- phase C: LDS counting sort, streamed coalesced write ----------------

__global__ __launch_bounds__(256) void pC_k(const int* __restrict__ src,
    const int* __restrict__ dst, const int* __restrict__ gscan,
    u32* __restrict__ elist, int E){
  __shared__ int A[NB];        // hist -> excl -> delta
  __shared__ int B[NB];        // running local position
  __shared__ int sp[256];
  __shared__ u32 pay[CHUNK];
  __shared__ u16 bkt[CHUNK];
  int t = threadIdx.x, blk = blockIdx.x;
  for (int j = t; j < NB; j += 256) A[j] = 0;
  __syncthreads();
  int e0 = blk*CHUNK, e1 = e0 + CHUNK; if (e1 > E) e1 = E;
  int cnt = e1 - e0;
  for (int e = e0 + t; e < e1; e += 256) atomicAdd(&A[dst[e] >> BSH], 1);
  __syncthreads();
  {
    int base = t*7;
    int cv[7]; int s = 0;
    #pragma unroll
    for (int j=0;j<7;++j){ int idx = base+j; cv[j] = (idx < NB) ? A[idx] : 0; s += cv[j]; }
    sp[t] = s; __syncthreads();
    for (int off=1; off<256; off<<=1){
      int x = (t>=off) ? sp[t-off] : 0;
      __syncthreads();
      sp[t] += x;
      __syncthreads();
    }
    int run = sp[t] - s;
    #pragma unroll
    for (int j=0;j<7;++j){
      int idx = base+j;
      if (idx < NB){ A[idx] = run; B[idx] = run; run += cv[j]; }
    }
  }
  __syncthreads();
  for (int j = t; j < NB; j += 256) A[j] = gscan[j*NBLK + blk] - A[j];
  __syncthreads();
  for (int e = e0 + t; e < e1; e += 256){
    int d = dst[e];
    int b = d >> BSH;
    u32 w = ((u32)(d & (BNODES-1)) << 17) | (u32)src[e];
    int r = atomicAdd(&B[b], 1);
    pay[r] = w; bkt[r] = (u16)b;
  }
  __syncthreads();
  for (int i = t; i < cnt; i += 256){
    int b = bkt[i];
    elist[i + A[b]] = pay[i];
  }
}

// ---------------- per-bucket counting sort (in place) + degrees ----------------

__global__ __launch_bounds__(256) void csr_k(u32* __restrict__ elist,
    const int* __restrict__ bstart, int* __restrict__ offs, int* __restrict__ degs,
    float* __restrict__ invd, int M){
  __shared__ int hist[BNODES];
  __shared__ int pos[BNODES];
  __shared__ u32 buf[BCAP];
  __shared__ u32 buf2[BCAP];
  int b = blockIdx.x, t = threadIdx.x;
  if (t < BNODES) hist[t] = 0;
  __syncthreads();
  int s0 = bstart[b];
  int cnt = bstart[b+1] - s0; if (cnt > BCAP) cnt = BCAP;
  u32* el = elist + s0;
  for (int e = t; e < cnt; e += 256){
    u32 w = el[e];
    buf[e] = w;
    atomicAdd(&hist[w>>17], 1);
  }
  __syncthreads();
  if (t < BNODES){
    int v = hist[t];
    int s = v;
    for (int off = 1; off < BNODES; off <<= 1){
      int x = __shfl_up(s, off);
      if (t >= off) s += x;
    }
    int excl = s - v;
    pos[t] = excl;
    int node = b*BNODES + t;
    if (node < M){
      offs[node] = s0 + excl;
      degs[node] = v;
      invd[node] = 1.f / fmaxf((float)v, 1.f);
    }
  }
  __syncthreads();
  for (int e = t; e < cnt; e += 256){
    u32 w = buf[e];
    int p = atomicAdd(&pos[w>>17], 1);
    buf2[p] = w & 0x1FFFFu;
  }
  __syncthreads();
  for (int e = t; e < cnt; e += 256) el[e] = buf2[e];
}

// ---------------- merged conversion: feats->sliced bf16, 4x weight transpose, zero pads ----

__global__ __launch_bounds__(256) void conv_k(const float* __restrict__ feats,
    const float* __restrict__ W0, const float* __restrict__ W1,
    const float* __restrict__ W2, const float* __restrict__ W3,
    u16* __restrict__ hb, u16* __restrict__ h2,
    u16* __restrict__ Wt0, u16* __restrict__ Wt1,
    u16* __restrict__ Wt2, u16* __restrict__ Wt3){
  int i = blockIdx.x*256 + threadIdx.x;
  const int NF4 = NODES*32;                     // float4 groups of features
  if (i < NF4){
    int n = i >> 5, f4 = i & 31;
    float4 x = ((const float4*)feats)[i];
    uint2 r;
    r.x = (u32)f2b(x.x) | ((u32)f2b(x.y) << 16);
    r.y = (u32)f2b(x.z) | ((u32)f2b(x.w) << 16);
    int sl = f4 >> 2, inner = (f4 & 3)*4;
    *(uint2*)(hb + (size_t)sl*SLST + n*16 + inner) = r;
    return;
  }
  i -= NF4;
  if (i < 3*16384){                             // W0..W2 transpose [K][N]->[N][K]
    int w = i / 16384, r = i % 16384;
    const float* W = (w==0) ? W0 : (w==1) ? W1 : W2;
    u16* Wt = (w==0) ? Wt0 : (w==1) ? Wt1 : Wt2;
    int k = r >> 7, nn = r & 127;
    Wt[nn*128 + k] = f2b(W[r]);
    return;
  }
  i -= 3*16384;
  if (i < 2048){                                // W3 transpose
    int k = i >> 4, nn = i & 15;
    Wt3[nn*128 + k] = f2b(W3[i]);
    return;
  }
  i -= 2048;
  if (i < 256){                                 // zero pad rows
    int buf = i >> 7, j = i & 127;
    int sl = j >> 4, inner = j & 15;
    u16* h = buf ? h2 : hb;
    h[(size_t)sl*SLST + NODES*16 + inner] = 0;
  }
}

// ---------------- sliced aggregation (lean): z = (1+eps)h + mean_agg(h) ----
// grid = NB*8; slice = blockIdx & 7 -> XCD-pinned under round-robin dispatch.
// thread = (node, feat-quad): t>>2 = node-in-bucket, t&3 = uint2 quad (4 feats).
// Private accumulators -> NO shuffles; 4-deep unrolled gather for MLP;
// z-store: thread t writes block_base + t -> fully coalesced.

__global__ __launch_bounds__(256) void aggS_k(const u16* __restrict__ hs,
    const u32* __restrict__ el_g, const int* __restrict__ bstart,
    const int* __restrict__ offs, const int* __restrict__ degs,
    const float* __restrict__ invd, const float* __restrict__ epsv, int ei,
    u16* __restrict__ zs, int M){
  __shared__ u32 el[BCAP];
  int blk = blockIdx.x;
  int s = blk & 7;
  int b = blk >> 3;
  int t = threadIdx.x;
  int s0 = bstart[b];
  int cnt = bstart[b+1] - s0; if (cnt > BCAP) cnt = BCAP;
  for (int i = t; i < cnt; i += 256) el[i] = el_g[s0 + i];
  __syncthreads();
  int n = b*64 + (t >> 2);
  if (n >= M) return;
  int c = t & 3;
  const uint2* __restrict__ hsl = (const uint2*)(hs + (size_t)s*SLST);
  uint2* __restrict__ zsl = (uint2*)(zs + (size_t)s*SLST);
  int st = offs[n] - s0, d = degs[n];
  float a0=0.f, a1=0.f, a2=0.f, a3=0.f;
  int j = 0;
  for (; j + 4 <= d; j += 4){
    int i0 = (int)el[st+j],   i1 = (int)el[st+j+1];
    int i2 = (int)el[st+j+2], i3 = (int)el[st+j+3];
    uint2 p0 = hsl[(size_t)i0*4 + c];
    uint2 p1 = hsl[(size_t)i1*4 + c];
    uint2 p2 = hsl[(size_t)i2*4 + c];
    uint2 p3 = hsl[(size_t)i3*4 + c];
    a0 += blo(p0.x)+blo(p1.x)+blo(p2.x)+blo(p3.x);
    a1 += bhi(p0.x)+bhi(p1.x)+bhi(p2.x)+bhi(p3.x);
    a2 += blo(p0.y)+blo(p1.y)+blo(p2.y)+blo(p3.y);
    a3 += bhi(p0.y)+bhi(p1.y)+bhi(p2.y)+bhi(p3.y);
  }
  for (; j < d; ++j){
    uint2 p = hsl[(size_t)((int)el[st+j])*4 + c];
    a0 += blo(p.x); a1 += bhi(p.x); a2 += blo(p.y); a3 += bhi(p.y);
  }
  uint2 pv = hsl[(size_t)n*4 + c];
  float inv = invd[n], e1s = 1.f + epsv[ei];
  uint2 r;
  r.x = (u32)f2b(e1s*blo(pv.x) + inv*a0) | ((u32)f2b(e1s*bhi(pv.x) + inv*a1) << 16);
  r.y = (u32)f2b(e1s*blo(pv.y) + inv*a2) | ((u32)f2b(e1s*bhi(pv.y) + inv*a3) << 16);
  zsl[(size_t)n*4 + c] = r;
}

// ---------------- GEMM with epilogue: h' = act(z @ W + b), sliced in / sliced or f32 out ----

template<int NT, bool RELU>
__global__ __launch_bounds__(256) void gemmE_k(const u16* __restrict__ zs,
    const u16* __restrict__ Wt, const float* __restrict__ bias,
    u16* __restrict__ hout, float* __restrict__ fout, int M){
  int lane = threadIdx.x & 63;
  int wave = threadIdx.x >> 6;
  int m = lane & 15;
  int q = lane >> 4;
  int row0 = (blockIdx.x*4 + wave)*16;
  if (row0 >= M) return;
  int rowA = row0 + m; if (rowA > M-1) rowA = M-1;
  // A from sliced z: f = kk + q*8 -> slice f>>4, inner (q&1)*8
  const u16* pa = zs + (size_t)(q>>1)*SLST + (size_t)rowA*16 + (q&1)*8;

  f32x4 acc[NT];
  #pragma unroll
  for (int j=0;j<NT;++j) acc[j] = (f32x4){0.f,0.f,0.f,0.f};

  #pragma unroll
  for (int kk=0; kk<128; kk+=32){
    short8 a = *(const short8*)(pa + (size_t)(kk>>4)*SLST);
    #pragma unroll
    for (int j=0;j<NT;++j){
      short8 bf = *(const short8*)(Wt + (j*16 + m)*128 + kk + q*8);
      acc[j] = __builtin_amdgcn_mfma_f32_16x16x32_bf16(a, bf, acc[j], 0, 0, 0);
    }
  }

  #pragma unroll
  for (int j=0;j<NT;++j){
    float bj = bias[j*16 + m];
    #pragma unroll
    for (int r=0;r<4;++r){
      int gn = row0 + q*4 + r;                   // C/D: row = q*4 + r, col = m
      if (gn < M){
        float o = acc[j][r] + bj;
        if (RELU) o = fmaxf(o, 0.f);
        if (NT == 8) hout[(size_t)j*SLST + (size_t)gn*16 + m] = f2b(o);
        else         fout[(size_t)gn*16 + m] = o;
      }
    }
  }
}

// ---------------- launch ----------------

extern "C" void kernel_launch(void* const* d_in, const int* in_sizes, int n_in,
                              void* d_out, int out_size, void* d_ws, size_t ws_size,
                              hipStream_t stream){
  const float* feats = (const float*)d_in[0];
  const int*   src   = (const int*)d_in[1];
  const int*   dst   = (const int*)d_in[2];
  const float* W0 = (const float*)d_in[3];  const float* b0 = (const float*)d_in[4];
  const float* W1 = (const float*)d_in[5];  const float* b1 = (const float*)d_in[6];
  const float* W2 = (const float*)d_in[7];  const float* b2 = (const float*)d_in[8];
  const float* W3 = (const float*)d_in[9];  const float* b3 = (const float*)d_in[10];
  const float* eps = (const float*)d_in[11];

  char* w = (char*)d_ws;
  auto alloc = [&](size_t bytes)->char*{
    char* p = w; w += (bytes + 255) & ~(size_t)255; return p;
  };
  int*  gh    = (int*)alloc(sizeof(int)*NHIST);
  int*  gscan = (int*)alloc(sizeof(int)*NHIST);
  int*  bsum  = (int*)alloc(sizeof(int)*256);
  int*  boff  = (int*)alloc(sizeof(int)*256);
  int*  bstart= (int*)alloc(sizeof(int)*(NB+1));
  int*  offs  = (int*)alloc(sizeof(int)*NODES);
  int*  degs  = (int*)alloc(sizeof(int)*NODES);
  float* invd = (float*)alloc(sizeof(float)*NODES);
  u32*  elist = (u32*)alloc(sizeof(u32)*EDGES);
  u16*  hb    = (u16*)alloc(sizeof(u16)*(size_t)8*SLST);
  u16*  h2    = (u16*)alloc(sizeof(u16)*(size_t)8*SLST);
  u16*  zsb   = (u16*)alloc(sizeof(u16)*(size_t)8*SLST);
  u16*  Wt0   = (u16*)alloc(sizeof(u16)*128*128);
  u16*  Wt1   = (u16*)alloc(sizeof(u16)*128*128);
  u16*  Wt2   = (u16*)alloc(sizeof(u16)*128*128);
  u16*  Wt3   = (u16*)alloc(sizeof(u16)*16*128);

  // ---- deterministic 3-phase partition -> dense bucketed elist, per-node CSR ----
  pA_k<<<NBLK, 256, 0, stream>>>(dst, gh, EDGES);
  int snb = (NHIST + 2047)/2048;                 // 150 <= 256
  scan1_k<<<snb, 256, 0, stream>>>(gh, gscan, bsum, NHIST);
  scan2_k<<<1, 256, 0, stream>>>(bsum, boff, snb);
  scan3_k<<<(NHIST+255)/256, 256, 0, stream>>>(gscan, boff, bstart, NHIST);
  pC_k<<<NBLK, 256, 0, stream>>>(src, dst, gscan, elist, EDGES);
  csr_k<<<NB, 256, 0, stream>>>(elist, bstart, offs, degs, invd, NODES);

  // ---- conversions (sliced h layout) + weight transposes + pad-row zeros ----
  {
    int total = NODES*32 + 3*16384 + 2048 + 256;
    conv_k<<<(total+255)/256, 256, 0, stream>>>(feats, W0, W1, W2, W3,
                                                hb, h2, Wt0, Wt1, Wt2, Wt3);
  }

  int gblocks = (NODES + 63)/64;
  int sblocks = NB*8;

  // layer l: z = (1+eps_l)h + mean_agg(h);  h' = relu(z@W_l + b_l)
  aggS_k<<<sblocks, 256, 0, stream>>>(hb, elist, bstart, offs, degs, invd, eps, 0, zsb, NODES);
  gemmE_k<8,true><<<gblocks, 256, 0, stream>>>(zsb, Wt0, b0, h2, nullptr, NODES);
  aggS_k<<<sblocks, 256, 0, stream>>>(h2, elist, bstart, offs, degs, invd, eps, 1, zsb, NODES);
  gemmE_k<8,true><<<gblocks, 256, 0, stream>>>(zsb, Wt1, b1, hb, nullptr, NODES);
  aggS_k<<<sblocks, 256, 0, stream>>>(hb, elist, bstart, offs, degs, invd, eps, 2, zsb, NODES);
  gemmE_k<8,true><<<gblocks, 256, 0, stream>>>(zsb, Wt2, b2, h2, nullptr, NODES);

  // layer 3: z = (1+eps_3)h + mean_agg(h); out = z@W3 + b3 (f32, no relu)
  aggS_k<<<sblocks, 256, 0, stream>>>(h2, elist, bstart, offs, degs, invd, eps, 3, zsb, NODES);
  gemmE_k<1,false><<<gblocks, 256, 0, stream>>>(zsb, Wt3, b3, nullptr, (float*)d_out, NODES);
}

// Round 9
// 545.552 us; speedup vs baseline: 1.8194x; 1.0158x over previous
//
#include <hip/hip_runtime.h>

#define NODES 100000
#define EDGES 1600000
#define FEATS 128
#define NCLS  16

// bucket = 64 consecutive dst nodes
#define BSH    6
#define BNODES 64
#define NB     ((NODES + BNODES - 1) / BNODES)   // 1563
#define CHUNK  8192
#define NBLK   ((EDGES + CHUNK - 1) / CHUNK)     // 196
#define NHIST  (NB * NBLK)                       // 306348
#define BCAP   2048                              // per-bucket LDS capacity
#define PAIRCAP 4096                             // bucket-pair capacity (mean 2048)
#define SLST   ((NODES + 1) * 16)                // u16 elems per 16-feat slice (+pad row)

typedef unsigned int  u32;
typedef unsigned short u16;
typedef __attribute__((ext_vector_type(8))) short short8;
typedef __attribute__((ext_vector_type(4))) float f32x4;

__device__ __forceinline__ u16 f2b(float f){
  u32 u = __float_as_uint(f);
  u += 0x7fffu + ((u>>16)&1u);   // RNE
  return (u16)(u>>16);
}
__device__ __forceinline__ float blo(u32 p){ return __uint_as_float(p<<16); }
__device__ __forceinline__ float bhi(u32 p){ return __uint_as_float(p & 0xffff0000u); }

// ---------------- phase A: per-chunk bucket histogram ----------------

__global__ __launch_bounds__(256) void pA_k(const int* __restrict__ dst,
                                            int* __restrict__ gh, int E){
  __shared__ int hist[NB];
  int t = threadIdx.x, blk = blockIdx.x;
  for (int j = t; j < NB; j += 256) hist[j] = 0;
  __syncthreads();
  int e0 = blk*CHUNK, e1 = e0 + CHUNK; if (e1 > E) e1 = E;
  for (int e = e0 + t; e < e1; e += 256) atomicAdd(&hist[dst[e] >> BSH], 1);
  __syncthreads();
  for (int j = t; j < NB; j += 256) gh[j*NBLK + blk] = hist[j];
}

// ---------------- phase B: exclusive scan of gh ----------------

__global__ __launch_bounds__(256) void scan1_k(const int* __restrict__ in, int* __restrict__ out,
                                               int* __restrict__ bsum, int n){
  __shared__ int sh[256];
  int t = threadIdx.x;
  int base = blockIdx.x*2048 + t*8;
  int v[8]; int s = 0;
  #pragma unroll
  for (int j=0;j<8;++j) v[j] = (base+j < n) ? in[base+j] : 0;
  #pragma unroll
  for (int j=0;j<8;++j){ int tmp = v[j]; v[j] = s; s += tmp; }
  sh[t] = s; __syncthreads();
  for (int off=1; off<256; off<<=1){
    int x = (t>=off) ? sh[t-off] : 0;
    __syncthreads();
    sh[t] += x;
    __syncthreads();
  }
  int excl = sh[t] - s;
  #pragma unroll
  for (int j=0;j<8;++j) if (base+j < n) out[base+j] = excl + v[j];
  if (t == 255) bsum[blockIdx.x] = sh[255];
}

__global__ __launch_bounds__(256) void scan2_k(const int* __restrict__ bsum,
                                               int* __restrict__ boff, int nb){
  __shared__ int sh[256];
  int t = threadIdx.x;
  int v = (t < nb) ? bsum[t] : 0;
  sh[t] = v; __syncthreads();
  for (int off=1; off<256; off<<=1){
    int x = (t>=off) ? sh[t-off] : 0;
    __syncthreads();
    sh[t] += x;
    __syncthreads();
  }
  if (t < nb) boff[t] = sh[t] - v;
}

__global__ void scan3_k(int* __restrict__ gscan, const int* __restrict__ boff,
                        int* __restrict__ bstart, int n){
  int i = blockIdx.x*256 + threadIdx.x;
  if (i < n){
    int v = gscan[i] + boff[i>>11];
    gscan[i] = v;
    if (i % NBLK == 0) bstart[i / NBLK] = v;
    if (i == 0) bstart[NB] = EDGES;
  }
}

// ---------------- phase C: LDS counting sort, streamed coalesced write ----------------

__global__ __launch_bounds__(256) void pC_k(const int* __restrict__ src,
    const int* __restrict__ dst, const int* __restrict__ gscan,
    u32* __restrict__ elist, int E){
  __shared__ int A[NB];        // hist -> excl -> delta
  __shared__ int B[NB];        // running local position
  __shared__ int sp[256];
  __shared__ u32 pay[CHUNK];
  __shared__ u16 bkt[CHUNK];
  int t = threadIdx.x, blk = blockIdx.x;
  for (int j = t; j < NB; j += 256) A[j] = 0;
  __syncthreads();
  int e0 = blk*CHUNK, e1 = e0 + CHUNK; if (e1 > E) e1 = E;
  int cnt = e1 - e0;
  for (int e = e0 + t; e < e1; e += 256) atomicAdd(&A[dst[e] >> BSH], 1);
  __syncthreads();
  {
    int base = t*7;
    int cv[7]; int s = 0;
    #pragma unroll
    for (int j=0;j<7;++j){ int idx = base+j; cv[j] = (idx < NB) ? A[idx] : 0; s += cv[j]; }
    sp[t] = s; __syncthreads();
    for (int off=1; off<256; off<<=1){
      int x = (t>=off) ? sp[t-off] : 0;
      __syncthreads();
      sp[t] += x;
      __syncthreads();
    }
    int run = sp[t] - s;
    #pragma unroll
    for (int j=0;j<7;++j){
      int idx = base+j;
      if (idx < NB){ A[idx] = run; B[idx] = run; run += cv[j]; }
    }
  }
  __syncthreads();
  for (int j = t; j < NB; j += 256) A[j] = gscan[j*NBLK + blk] - A[j];
  __syncthreads();
  for (int e = e0 + t; e < e1; e += 256){
    int d = dst[e];
    int b = d >> BSH;
    u32 w = ((u32)(d & (BNODES-1)) << 17) | (u32)src[e];
    int r = atomicAdd(&B[b], 1);
    pay[r] = w; bkt[r] = (u16)b;
  }
  __syncthreads();
  for (int i = t; i < cnt; i += 256){
    int b = bkt[i];
    elist[i + A[b]] = pay[i];
  }
}

// ---------------- per-bucket counting sort (in place) + degrees ----------------

__global__ __launch_bounds__(256) void csr_k(u32* __restrict__ elist,
    const int* __restrict__ bstart, int* __restrict__ offs, int* __restrict__ degs,
    float* __restrict__ invd, int M){
  __shared__ int hist[BNODES];
  __shared__ int pos[BNODES];
  __shared__ u32 buf[BCAP];
  __shared__ u32 buf2[BCAP];
  int b = blockIdx.x, t = threadIdx.x;
  if (t < BNODES) hist[t] = 0;
  __syncthreads();
  int s0 = bstart[b];
  int cnt = bstart[b+1] - s0; if (cnt > BCAP) cnt = BCAP;
  u32* el = elist + s0;
  for (int e = t; e < cnt; e += 256){
    u32 w = el[e];
    buf[e] = w;
    atomicAdd(&hist[w>>17], 1);
  }
  __syncthreads();
  if (t < BNODES){
    int v = hist[t];
    int s = v;
    for (int off = 1; off < BNODES; off <<= 1){
      int x = __shfl_up(s, off);
      if (t >= off) s += x;
    }
    int excl = s - v;
    pos[t] = excl;
    int node = b*BNODES + t;
    if (node < M){
      offs[node] = s0 + excl;
      degs[node] = v;
      invd[node] = 1.f / fmaxf((float)v, 1.f);
    }
  }
  __syncthreads();
  for (int e = t; e < cnt; e += 256){
    u32 w = buf[e];
    int p = atomicAdd(&pos[w>>17], 1);
    buf2[p] = w & 0x1FFFFu;
  }
  __syncthreads();
  for (int e = t; e < cnt; e += 256) el[e] = buf2[e];
}

// ---------------- merged conversion: feats->sliced bf16, 4x weight transpose, zero pads ----

__global__ __launch_bounds__(256) void conv_k(const float* __restrict__ feats,
    const float* __restrict__ W0, const float* __restrict__ W1,
    const float* __restrict__ W2, const float* __restrict__ W3,
    u16* __restrict__ hb, u16* __restrict__ h2,
    u16* __restrict__ Wt0, u16* __restrict__ Wt1,
    u16* __restrict__ Wt2, u16* __restrict__ Wt3){
  int i = blockIdx.x*256 + threadIdx.x;
  const int NF4 = NODES*32;                     // float4 groups of features
  if (i < NF4){
    int n = i >> 5, f4 = i & 31;
    float4 x = ((const float4*)feats)[i];
    uint2 r;
    r.x = (u32)f2b(x.x) | ((u32)f2b(x.y) << 16);
    r.y = (u32)f2b(x.z) | ((u32)f2b(x.w) << 16);
    int sl = f4 >> 2, inner = (f4 & 3)*4;
    *(uint2*)(hb + (size_t)sl*SLST + n*16 + inner) = r;
    return;
  }
  i -= NF4;
  if (i < 3*16384){                             // W0..W2 transpose [K][N]->[N][K]
    int w = i / 16384, r = i % 16384;
    const float* W = (w==0) ? W0 : (w==1) ? W1 : W2;
    u16* Wt = (w==0) ? Wt0 : (w==1) ? Wt1 : Wt2;
    int k = r >> 7, nn = r & 127;
    Wt[nn*128 + k] = f2b(W[r]);
    return;
  }
  i -= 3*16384;
  if (i < 2048){                                // W3 transpose
    int k = i >> 4, nn = i & 15;
    Wt3[nn*128 + k] = f2b(W3[i]);
    return;
  }
  i -= 2048;
  if (i < 256){                                 // zero pad rows
    int buf = i >> 7, j = i & 127;
    int sl = j >> 4, inner = j & 15;
    u16* h = buf ? h2 : hb;
    h[(size_t)sl*SLST + NODES*16 + inner] = 0;
  }
}

// ---------------- sliced aggregation v3: z = (1+eps)h + mean_agg(h) ----
// grid = ceil(NB/2)*8; slice = blk & 7 (XCD-pinned); block = bucket PAIR (128 nodes).
// thread = (node, 8-feat half): t>>1 = node-in-pair, t&1 = uint4 half.
// uint4 gathers (16 B), 8-deep unroll -> 128 B in flight per lane; no shuffles.

__global__ __launch_bounds__(256) void aggS_k(const u16* __restrict__ hs,
    const u32* __restrict__ el_g, const int* __restrict__ bstart,
    const int* __restrict__ offs, const int* __restrict__ degs,
    const float* __restrict__ invd, const float* __restrict__ epsv, int ei,
    u16* __restrict__ zs, int M){
  __shared__ u32 el[PAIRCAP];
  int blk = blockIdx.x;
  int s = blk & 7;
  int bp = blk >> 3;
  int b0 = bp*2;
  int t = threadIdx.x;
  int bend = b0 + 2; if (bend > NB) bend = NB;
  int s0 = bstart[b0];
  int cnt = bstart[bend] - s0; if (cnt > PAIRCAP) cnt = PAIRCAP;
  for (int i = t; i < cnt; i += 256) el[i] = el_g[s0 + i];
  __syncthreads();
  int n = b0*64 + (t >> 1);
  if (n >= M) return;
  int hh = t & 1;
  const uint4* __restrict__ hsl = (const uint4*)(hs + (size_t)s*SLST);
  uint4* __restrict__ zsl = (uint4*)(zs + (size_t)s*SLST);
  int st = offs[n] - s0, d = degs[n];
  float a0=0.f,a1=0.f,a2=0.f,a3=0.f,a4=0.f,a5=0.f,a6=0.f,a7=0.f;
  int j = 0;
  for (; j + 8 <= d; j += 8){
    int i0 = (int)el[st+j],   i1 = (int)el[st+j+1];
    int i2 = (int)el[st+j+2], i3 = (int)el[st+j+3];
    int i4 = (int)el[st+j+4], i5 = (int)el[st+j+5];
    int i6 = (int)el[st+j+6], i7 = (int)el[st+j+7];
    uint4 p0 = hsl[(size_t)i0*2 + hh];
    uint4 p1 = hsl[(size_t)i1*2 + hh];
    uint4 p2 = hsl[(size_t)i2*2 + hh];
    uint4 p3 = hsl[(size_t)i3*2 + hh];
    uint4 p4 = hsl[(size_t)i4*2 + hh];
    uint4 p5 = hsl[(size_t)i5*2 + hh];
    uint4 p6 = hsl[(size_t)i6*2 + hh];
    uint4 p7 = hsl[(size_t)i7*2 + hh];
    a0 += blo(p0.x)+blo(p1.x)+blo(p2.x)+blo(p3.x)+blo(p4.x)+blo(p5.x)+blo(p6.x)+blo(p7.x);
    a1 += bhi(p0.x)+bhi(p1.x)+bhi(p2.x)+bhi(p3.x)+bhi(p4.x)+bhi(p5.x)+bhi(p6.x)+bhi(p7.x);
    a2 += blo(p0.y)+blo(p1.y)+blo(p2.y)+blo(p3.y)+blo(p4.y)+blo(p5.y)+blo(p6.y)+blo(p7.y);
    a3 += bhi(p0.y)+bhi(p1.y)+bhi(p2.y)+bhi(p3.y)+bhi(p4.y)+bhi(p5.y)+bhi(p6.y)+bhi(p7.y);
    a4 += blo(p0.z)+blo(p1.z)+blo(p2.z)+blo(p3.z)+blo(p4.z)+blo(p5.z)+blo(p6.z)+blo(p7.z);
    a5 += bhi(p0.z)+bhi(p1.z)+bhi(p2.z)+bhi(p3.z)+bhi(p4.z)+bhi(p5.z)+bhi(p6.z)+bhi(p7.z);
    a6 += blo(p0.w)+blo(p1.w)+blo(p2.w)+blo(p3.w)+blo(p4.w)+blo(p5.w)+blo(p6.w)+blo(p7.w);
    a7 += bhi(p0.w)+bhi(p1.w)+bhi(p2.w)+bhi(p3.w)+bhi(p4.w)+bhi(p5.w)+bhi(p6.w)+bhi(p7.w);
  }
  for (; j < d; ++j){
    uint4 p = hsl[(size_t)((int)el[st+j])*2 + hh];
    a0 += blo(p.x); a1 += bhi(p.x);
    a2 += blo(p.y); a3 += bhi(p.y);
    a4 += blo(p.z); a5 += bhi(p.z);
    a6 += blo(p.w); a7 += bhi(p.w);
  }
  uint4 pv = hsl[(size_t)n*2 + hh];
  float inv = invd[n], e1s = 1.f + epsv[ei];
  uint4 r;
  r.x = (u32)f2b(e1s*blo(pv.x) + inv*a0) | ((u32)f2b(e1s*bhi(pv.x) + inv*a1) << 16);
  r.y = (u32)f2b(e1s*blo(pv.y) + inv*a2) | ((u32)f2b(e1s*bhi(pv.y) + inv*a3) << 16);
  r.z = (u32)f2b(e1s*blo(pv.z) + inv*a4) | ((u32)f2b(e1s*bhi(pv.z) + inv*a5) << 16);
  r.w = (u32)f2b(e1s*blo(pv.w) + inv*a6) | ((u32)f2b(e1s*bhi(pv.w) + inv*a7) << 16);
  zsl[(size_t)n*2 + hh] = r;
}

// ---------------- GEMM with epilogue: h' = act(z @ W + b), sliced in / sliced or f32 out ----

template<int NT, bool RELU>
__global__ __launch_bounds__(256) void gemmE_k(const u16* __restrict__ zs,
    const u16* __restrict__ Wt, const float* __restrict__ bias,
    u16* __restrict__ hout, float* __restrict__ fout, int M){
  int lane = threadIdx.x & 63;
  int wave = threadIdx.x >> 6;
  int m = lane & 15;
  int q = lane >> 4;
  int row0 = (blockIdx.x*4 + wave)*16;
  if (row0 >= M) return;
  int rowA = row0 + m; if (rowA > M-1) rowA = M-1;
  // A from sliced z: f = kk + q*8 -> slice f>>4, inner (q&1)*8
  const u16* pa = zs + (size_t)(q>>1)*SLST + (size_t)rowA*16 + (q&1)*8;

  f32x4 acc[NT];
  #pragma unroll
  for (int j=0;j<NT;++j) acc[j] = (f32x4){0.f,0.f,0.f,0.f};

  #pragma unroll
  for (int kk=0; kk<128; kk+=32){
    short8 a = *(const short8*)(pa + (size_t)(kk>>4)*SLST);
    #pragma unroll
    for (int j=0;j<NT;++j){
      short8 bf = *(const short8*)(Wt + (j*16 + m)*128 + kk + q*8);
      acc[j] = __builtin_amdgcn_mfma_f32_16x16x32_bf16(a, bf, acc[j], 0, 0, 0);
    }
  }

  #pragma unroll
  for (int j=0;j<NT;++j){
    float bj = bias[j*16 + m];
    #pragma unroll
    for (int r=0;r<4;++r){
      int gn = row0 + q*4 + r;                   // C/D: row = q*4 + r, col = m
      if (gn < M){
        float o = acc[j][r] + bj;
        if (RELU) o = fmaxf(o, 0.f);
        if (NT == 8) hout[(size_t)j*SLST + (size_t)gn*16 + m] = f2b(o);
        else         fout[(size_t)gn*16 + m] = o;
      }
    }
  }
}

// ---------------- launch ----------------

extern "C" void kernel_launch(void* const* d_in, const int* in_sizes, int n_in,
                              void* d_out, int out_size, void* d_ws, size_t ws_size,
                              hipStream_t stream){
  const float* feats = (const float*)d_in[0];
  const int*   src   = (const int*)d_in[1];
  const int*   dst   = (const int*)d_in[2];
  const float* W0 = (const float*)d_in[3];  const float* b0 = (const float*)d_in[4];
  const float* W1 = (const float*)d_in[5];  const float* b1 = (const float*)d_in[6];
  const float* W2 = (const float*)d_in[7];  const float* b2 = (const float*)d_in[8];
  const float* W3 = (const float*)d_in[9];  const float* b3 = (const float*)d_in[10];
  const float* eps = (const float*)d_in[11];

  char* w = (char*)d_ws;
  auto alloc = [&](size_t bytes)->char*{
    char* p = w; w += (bytes + 255) & ~(size_t)255; return p;
  };
  int*  gh    = (int*)alloc(sizeof(int)*NHIST);
  int*  gscan = (int*)alloc(sizeof(int)*NHIST);
  int*  bsum  = (int*)alloc(sizeof(int)*256);
  int*  boff  = (int*)alloc(sizeof(int)*256);
  int*  bstart= (int*)alloc(sizeof(int)*(NB+1));
  int*  offs  = (int*)alloc(sizeof(int)*NODES);
  int*  degs  = (int*)alloc(sizeof(int)*NODES);
  float* invd = (float*)alloc(sizeof(float)*NODES);
  u32*  elist = (u32*)alloc(sizeof(u32)*EDGES);
  u16*  hb    = (u16*)alloc(sizeof(u16)*(size_t)8*SLST);
  u16*  h2    = (u16*)alloc(sizeof(u16)*(size_t)8*SLST);
  u16*  zsb   = (u16*)alloc(sizeof(u16)*(size_t)8*SLST);
  u16*  Wt0   = (u16*)alloc(sizeof(u16)*128*128);
  u16*  Wt1   = (u16*)alloc(sizeof(u16)*128*128);
  u16*  Wt2   = (u16*)alloc(sizeof(u16)*128*128);
  u16*  Wt3   = (u16*)alloc(sizeof(u16)*16*128);

  // ---- deterministic 3-phase partition -> dense bucketed elist, per-node CSR ----
  pA_k<<<NBLK, 256, 0, stream>>>(dst, gh, EDGES);
  int snb = (NHIST + 2047)/2048;                 // 150 <= 256
  scan1_k<<<snb, 256, 0, stream>>>(gh, gscan, bsum, NHIST);
  scan2_k<<<1, 256, 0, stream>>>(bsum, boff, snb);
  scan3_k<<<(NHIST+255)/256, 256, 0, stream>>>(gscan, boff, bstart, NHIST);
  pC_k<<<NBLK, 256, 0, stream>>>(src, dst, gscan, elist, EDGES);
  csr_k<<<NB, 256, 0, stream>>>(elist, bstart, offs, degs, invd, NODES);

  // ---- conversions (sliced h layout) + weight transposes + pad-row zeros ----
  {
    int total = NODES*32 + 3*16384 + 2048 + 256;
    conv_k<<<(total+255)/256, 256, 0, stream>>>(feats, W0, W1, W2, W3,
                                                hb, h2, Wt0, Wt1, Wt2, Wt3);
  }

  int gblocks = (NODES + 63)/64;
  int sblocks = ((NB + 1)/2)*8;

  // layer l: z = (1+eps_l)h + mean_agg(h);  h' = relu(z@W_l + b_l)
  aggS_k<<<sblocks, 256, 0, stream>>>(hb, elist, bstart, offs, degs, invd, eps, 0, zsb, NODES);
  gemmE_k<8,true><<<gblocks, 256, 0, stream>>>(zsb, Wt0, b0, h2, nullptr, NODES);
  aggS_k<<<sblocks, 256, 0, stream>>>(h2, elist, bstart, offs, degs, invd, eps, 1, zsb, NODES);
  gemmE_k<8,true><<<gblocks, 256, 0, stream>>>(zsb, Wt1, b1, hb, nullptr, NODES);
  aggS_k<<<sblocks, 256, 0, stream>>>(hb, elist, bstart, offs, degs, invd, eps, 2, zsb, NODES);
  gemmE_k<8,true><<<gblocks, 256, 0, stream>>>(zsb, Wt2, b2, h2, nullptr, NODES);

  // layer 3: z = (1+eps_3)h + mean_agg(h); out = z@W3 + b3 (f32, no relu)
  aggS_k<<<sblocks, 256, 0, stream>>>(h2, elist, bstart, offs, degs, invd, eps, 3, zsb, NODES);
  gemmE_k<1,false><<<gblocks, 256, 0, stream>>>(zsb, Wt3, b3, nullptr, (float*)d_out, NODES);
}